// Round 6
// baseline (562.793 us; speedup 1.0000x reference)
//
#include <hip/hip_runtime.h>

// hidden = tanh(H @ h + C @ c); comm = hidden. H,C: [64,64]; h,c: [64, 524288].
#define NA 64
#define FD 524288
#define FD2 (FD / 2)   // 262144 float2 columns
#define ROWS 8         // output rows per wave; 8 waves/block cover all 64

// Session diagnosis (R4/R5 counters): VGPR_Count (24, 52) was SMALLER than
// the kernel's live float state (32, ~90) with WRITE_SIZE clean -> the
// overflow lived in AGPRs, i.e. every v_fmac was wrapped in
// v_accvgpr_read/write (3x VALU per FMA; explains R4's 189K/SIMD VALU
// cycles vs 47K pure-FMA). Fix #1: shrink per-wave state below the
// occupancy-driven VGPR budget: ROWS=8 -> acc[8] float2 = 16 VGPR, total
// ~40 -> fits 8 waves/SIMD (budget 64) with NO AGPR shuffling and ~100%
// occupancy.
//
// Fix #2 (R4's other stall): per j-step coefficients were 32 discrete
// stride-256B s_loads (sK$-thrashing batch stall). A setup kernel
// pre-transposes H/C into W[j][wave][16] (k<8: H[w*8+k][j], k>=8: C[...][j])
// in d_ws, so a wave's per-j coefficients are ONE contiguous 64B scalar
// batch, prefetched one j ahead into SGPRs. Coefficients cost 0 VGPR, 0 VALU.
__global__ void transpose_coeff(const float* __restrict__ Hm,
                                const float* __restrict__ Cm,
                                float* __restrict__ W)
{
    const int j = blockIdx.x;        // 0..63
    const int t = threadIdx.x;       // 0..127
    const int w = t >> 4;            // wave id in main kernel
    const int k = t & 15;
    const int row = w * ROWS + (k & 7);
    const float v = (k < 8) ? Hm[row * NA + j] : Cm[row * NA + j];
    W[j * 128 + t] = v;
}

__global__ __launch_bounds__(512) void linlayer_kernel(
    const float* __restrict__ h, const float* __restrict__ c,
    const float* __restrict__ W, float* __restrict__ out)
{
    const int t = threadIdx.x;
    const int lane = t & 63;
    int wb = (t >> 6) << 4;                     // wave's float offset in a W row
    wb = __builtin_amdgcn_readfirstlane(wb);    // force SGPR -> s_load path
    const int i0 = wb >> 1;                     // = wave * ROWS

    const int col2 = blockIdx.x * 64 + lane;    // this thread's float2 column
    // All 8 waves of a block read the SAME h/c segments -> L1 broadcast;
    // HBM traffic stays 1x.

    const float2* __restrict__ h2 = (const float2*)h;
    const float2* __restrict__ c2 = (const float2*)c;
    float2* __restrict__ o2 = (float2*)out;

    float2 acc[ROWS];
#pragma unroll
    for (int i = 0; i < ROWS; ++i) { acc[i].x = 0.f; acc[i].y = 0.f; }

    // 1-deep pipelines: data (hv/cv) and coefficients (Ha/Hb/Ca/Cb, SGPRs).
    const float4* __restrict__ W0 = (const float4*)(W + wb);
    float4 Ha = W0[0], Hb = W0[1], Ca = W0[2], Cb = W0[3];
    float2 hv = h2[col2];
    float2 cv = c2[col2];

#pragma unroll 1
    for (int j = 0; j < NA; ++j) {
        const int jn = (j + 1) & (NA - 1);  // clamped wrap: no branch, L1-hot
        const float4* __restrict__ Wn = (const float4*)(W + jn * 128 + wb);
        const float4 Han = Wn[0], Hbn = Wn[1], Can = Wn[2], Cbn = Wn[3];
        const float2 hn = h2[(size_t)jn * FD2 + col2];
        const float2 cn = c2[(size_t)jn * FD2 + col2];

        const float Hc[ROWS] = {Ha.x, Ha.y, Ha.z, Ha.w, Hb.x, Hb.y, Hb.z, Hb.w};
        const float Cc[ROWS] = {Ca.x, Ca.y, Ca.z, Ca.w, Cb.x, Cb.y, Cb.z, Cb.w};
#pragma unroll
        for (int i = 0; i < ROWS; ++i) {
            acc[i].x = fmaf(Hc[i], hv.x, fmaf(Cc[i], cv.x, acc[i].x));
            acc[i].y = fmaf(Hc[i], hv.y, fmaf(Cc[i], cv.y, acc[i].y));
        }

        Ha = Han; Hb = Hbn; Ca = Can; Cb = Cbn;
        hv = hn; cv = cn;
    }

    // tanh(x) = 1 - 2/(exp(2x)+1); saturates cleanly, no NaN.
#pragma unroll
    for (int i = 0; i < ROWS; ++i) {
        float2 tv;
        { const float e = __expf(2.0f * acc[i].x); tv.x = 1.0f - 2.0f / (e + 1.0f); }
        { const float e = __expf(2.0f * acc[i].y); tv.y = 1.0f - 2.0f / (e + 1.0f); }
        o2[(size_t)(i0 + i) * FD2 + col2] = tv;        // hidden
        o2[(size_t)(NA + i0 + i) * FD2 + col2] = tv;   // comm (same values)
    }
}

extern "C" void kernel_launch(void* const* d_in, const int* in_sizes, int n_in,
                              void* d_out, int out_size, void* d_ws, size_t ws_size,
                              hipStream_t stream) {
    const float* h  = (const float*)d_in[0];
    const float* c  = (const float*)d_in[1];
    const float* Hm = (const float*)d_in[2];
    const float* Cm = (const float*)d_in[3];
    float* out = (float*)d_out;
    float* W   = (float*)d_ws;   // 64*128*4 = 32 KB coefficient table

    hipLaunchKernelGGL(transpose_coeff, dim3(NA), dim3(128), 0, stream,
                       Hm, Cm, W);
    // Same stream -> W is visible to the main kernel (dispatch ordering).
    dim3 block(512);                 // 8 waves; wave w owns rows w*8..w*8+7
    dim3 grid(FD2 / 64);             // 4096 blocks x 64 float2 cols
    hipLaunchKernelGGL(linlayer_kernel, grid, block, 0, stream,
                       h, c, W, out);
}